// Round 1
// baseline (124.194 us; speedup 1.0000x reference)
//
#include <hip/hip_runtime.h>
#include <math.h>

#define B_  32
#define C_  256
#define H_  64
#define W_  64
#define HW  (H_*W_)          // 4096
#define HW4 (HW/4)           // 1024

__device__ __forceinline__ float clamp01(float v) {
    return fminf(fmaxf(v, 0.0f), 1.0f);
}

__device__ __forceinline__ float block_reduce_sum_256(float v, float* sm) {
    // wave64 shuffle reduce, then across 4 waves via LDS. Valid on thread 0.
    #pragma unroll
    for (int off = 32; off > 0; off >>= 1) v += __shfl_down(v, off, 64);
    int lane = threadIdx.x & 63, wid = threadIdx.x >> 6;
    if (lane == 0) sm[wid] = v;
    __syncthreads();
    float total = 0.0f;
    if (threadIdx.x == 0) total = sm[0] + sm[1] + sm[2] + sm[3];
    return total;
}

// Kernel A: per-batch block. boxes -> analytic mask -> conv1(3x3,16)+relu
// -> conv2(1x1)+sigmoid -> refined_mask out + area to ws. Also writes boxes out.
__global__ __launch_bounds__(256) void kern_mask(
    const float* __restrict__ xywh,
    const float* __restrict__ conv1_w, const float* __restrict__ conv1_b,
    const float* __restrict__ conv2_w, const float* __restrict__ conv2_b,
    float* __restrict__ out_boxes, float* __restrict__ out_rm,
    float* __restrict__ ws_area)
{
    const int b = blockIdx.x;
    const int t = threadIdx.x;

    __shared__ float sw1[16 * 9];
    __shared__ float sb1[16];
    __shared__ float sw2[16];
    __shared__ float sred[4];

    if (t < 144)                 sw1[t]       = conv1_w[t];
    else if (t < 160)            sb1[t - 144] = conv1_b[t - 144];
    else if (t < 176)            sw2[t - 160] = conv2_w[t - 160];
    const float b2v = conv2_b[0];

    // box math (replicated in every thread; scalar broadcast loads)
    const float xc = xywh[b * 4 + 0];
    const float yc = xywh[b * 4 + 1];
    const float bw = xywh[b * 4 + 2];
    const float bh = xywh[b * 4 + 3];

    float x1 = clamp01(xc - bw * 0.5f);
    float y1 = clamp01(yc - bh * 0.5f);
    float x2 = clamp01(xc + bw * 0.5f);
    float y2 = clamp01(yc + bh * 0.5f);
    float xl = fminf(x1, x2), xh = fmaxf(x1, x2);
    float yl = fminf(y1, y2), yh = fmaxf(y1, y2);
    float w_ = fmaxf(xh - xl, 1e-6f);
    float h_ = fmaxf(yh - yl, 1e-6f);
    float cx = (xh + xl) * 0.5f, cy = (yh + yl) * 0.5f;
    float bx1 = clamp01(cx - w_ * 0.5f);
    float by1 = clamp01(cy - h_ * 0.5f);
    float bx2 = clamp01(cx + w_ * 0.5f);
    float by2 = clamp01(cy + h_ * 0.5f);

    if (t == 0) {
        out_boxes[b * 4 + 0] = bx1;
        out_boxes[b * 4 + 1] = by1;
        out_boxes[b * 4 + 2] = bx2;
        out_boxes[b * 4 + 3] = by2;
    }

    float ww = fmaxf(bx2 - bx1, 1e-4f);
    float hh = fmaxf(by2 - by1, 1e-4f);
    float diag = sqrtf(ww * ww + hh * hh);
    float margin = fminf(fmaxf(diag * 0.2f, 0.02f), 0.2f);
    float mx1 = clamp01(bx1 - margin);
    float my1 = clamp01(by1 - margin);
    float mx2 = clamp01(bx2 + margin);
    float my2 = clamp01(by2 + margin);

    __syncthreads();

    float asum = 0.0f;
    for (int p = t; p < HW; p += 256) {
        const int y = p >> 6;
        const int x = p & 63;
        // 3x3 neighborhood mask values (pad=1 => zero outside)
        float mv[9];
        #pragma unroll
        for (int ky = 0; ky < 3; ++ky) {
            const int yy = y + ky - 1;
            float gy = (float)((double)yy / 63.0);
            bool yin = (yy >= 0) && (yy < H_) && (gy >= my1) && (gy <= my2);
            #pragma unroll
            for (int kx = 0; kx < 3; ++kx) {
                const int xx = x + kx - 1;
                float gx = (float)((double)xx / 63.0);
                bool xin = (xx >= 0) && (xx < W_) && (gx >= mx1) && (gx <= mx2);
                mv[ky * 3 + kx] = (yin && xin) ? 1.0f : 0.0f;
            }
        }
        float z = b2v;
        #pragma unroll
        for (int oc = 0; oc < 16; ++oc) {
            float hsum = sb1[oc];
            #pragma unroll
            for (int k = 0; k < 9; ++k) hsum = fmaf(mv[k], sw1[oc * 9 + k], hsum);
            z = fmaf(fmaxf(hsum, 0.0f), sw2[oc], z);
        }
        float rm = 1.0f / (1.0f + expf(-z));
        out_rm[b * HW + p] = rm;
        asum += rm;
    }

    float total = block_reduce_sum_256(asum, sred);
    if (t == 0) ws_area[b] = fmaxf(total, 1.0f);
}

// Kernel B: pointer_feat[b,c] = sum(feat[b,c,:,:] * rm[b,:,:]) / area[b]
__global__ __launch_bounds__(256) void kern_pf(
    const float* __restrict__ feat, const float* __restrict__ rm,
    const float* __restrict__ ws_area, float* __restrict__ out_pf)
{
    const int blk = blockIdx.x;          // (b*256 + c)
    const int b = blk >> 8;
    __shared__ float sred[4];

    const float4* f4 = (const float4*)(feat + (size_t)blk * HW);
    const float4* r4 = (const float4*)(rm + (size_t)b * HW);

    float s = 0.0f;
    for (int i = threadIdx.x; i < HW4; i += 256) {
        float4 f = f4[i];
        float4 r = r4[i];
        s = fmaf(f.x, r.x, s);
        s = fmaf(f.y, r.y, s);
        s = fmaf(f.z, r.z, s);
        s = fmaf(f.w, r.w, s);
    }
    float total = block_reduce_sum_256(s, sred);
    if (threadIdx.x == 0) out_pf[blk] = total / ws_area[b];
}

// Kernel C: hidden layers of both MLPs. One block per batch; thread t = neuron t.
__global__ __launch_bounds__(256) void kern_mlp1(
    const float* __restrict__ pf, const float* __restrict__ lang,
    const float* __restrict__ cg_w1, const float* __restrict__ cg_b1,
    const float* __restrict__ lf_w1, const float* __restrict__ lf_b1,
    float* __restrict__ h_cg, float* __restrict__ h_lf)
{
    const int b = blockIdx.x;
    const int t = threadIdx.x;
    __shared__ float fus[512];
    fus[t]       = pf[b * 256 + t];
    fus[256 + t] = lang[b * 256 + t];
    __syncthreads();

    const float4* wc = (const float4*)(cg_w1 + (size_t)t * 512);
    const float4* wl = (const float4*)(lf_w1 + (size_t)t * 512);
    const float4* fv = (const float4*)fus;
    float sc = 0.0f, sl = 0.0f;
    #pragma unroll 4
    for (int k = 0; k < 128; ++k) {
        float4 f = fv[k];
        float4 a = wc[k];
        float4 d = wl[k];
        sc = fmaf(f.x, a.x, fmaf(f.y, a.y, fmaf(f.z, a.z, fmaf(f.w, a.w, sc))));
        sl = fmaf(f.x, d.x, fmaf(f.y, d.y, fmaf(f.z, d.z, fmaf(f.w, d.w, sl))));
    }
    h_cg[b * 256 + t] = fmaxf(sc + cg_b1[t], 0.0f);
    h_lf[b * 256 + t] = fmaxf(sl + lf_b1[t], 0.0f);
}

// Kernel D: output layers. ch_gate -> ws, guided_lang -> out.
__global__ __launch_bounds__(256) void kern_mlp2(
    const float* __restrict__ h_cg, const float* __restrict__ h_lf,
    const float* __restrict__ cg_w2, const float* __restrict__ cg_b2,
    const float* __restrict__ lf_w2, const float* __restrict__ lf_b2,
    const float* __restrict__ lang,
    float* __restrict__ ws_cg, float* __restrict__ out_gl)
{
    const int b = blockIdx.x;
    const int t = threadIdx.x;
    __shared__ float shc[256];
    __shared__ float shl[256];
    shc[t] = h_cg[b * 256 + t];
    shl[t] = h_lf[b * 256 + t];
    __syncthreads();

    const float4* wc = (const float4*)(cg_w2 + (size_t)t * 256);
    const float4* wl = (const float4*)(lf_w2 + (size_t)t * 256);
    const float4* hc = (const float4*)shc;
    const float4* hl = (const float4*)shl;
    float sc = 0.0f, sl = 0.0f;
    #pragma unroll 4
    for (int k = 0; k < 64; ++k) {
        float4 a = wc[k], f = hc[k];
        sc = fmaf(f.x, a.x, fmaf(f.y, a.y, fmaf(f.z, a.z, fmaf(f.w, a.w, sc))));
        float4 d = wl[k], g = hl[k];
        sl = fmaf(g.x, d.x, fmaf(g.y, d.y, fmaf(g.z, d.z, fmaf(g.w, d.w, sl))));
    }
    float gate = 1.0f / (1.0f + expf(-(sc + cg_b2[t])));
    float ld = tanhf(sl + lf_b2[t]);
    ws_cg[b * 256 + t] = gate;
    out_gl[b * 256 + t] = lang[b * 256 + t] + 0.4f * ld;
}

// Kernel E: guided_feat = feat * (1 + 0.6*rm) * (1 + 0.5*cg). One block per (b,c) row.
__global__ __launch_bounds__(256) void kern_guided(
    const float* __restrict__ feat, const float* __restrict__ rm,
    const float* __restrict__ ws_cg, float* __restrict__ out_gf)
{
    const int blk = blockIdx.x;          // (b*256 + c)
    const int b = blk >> 8;
    const float g = 1.0f + 0.5f * ws_cg[blk];

    const float4* f4 = (const float4*)(feat + (size_t)blk * HW);
    const float4* r4 = (const float4*)(rm + (size_t)b * HW);
    float4* o4 = (float4*)(out_gf + (size_t)blk * HW);

    for (int i = threadIdx.x; i < HW4; i += 256) {
        float4 f = f4[i];
        float4 r = r4[i];
        float4 o;
        o.x = f.x * (1.0f + 0.6f * r.x) * g;
        o.y = f.y * (1.0f + 0.6f * r.y) * g;
        o.z = f.z * (1.0f + 0.6f * r.z) * g;
        o.w = f.w * (1.0f + 0.6f * r.w) * g;
        o4[i] = o;
    }
}

extern "C" void kernel_launch(void* const* d_in, const int* in_sizes, int n_in,
                              void* d_out, int out_size, void* d_ws, size_t ws_size,
                              hipStream_t stream) {
    const float* feat     = (const float*)d_in[0];
    const float* lang     = (const float*)d_in[1];
    const float* xywh     = (const float*)d_in[2];
    const float* conv1_w  = (const float*)d_in[3];
    const float* conv1_b  = (const float*)d_in[4];
    const float* conv2_w  = (const float*)d_in[5];
    const float* conv2_b  = (const float*)d_in[6];
    const float* cg_w1    = (const float*)d_in[7];
    const float* cg_b1    = (const float*)d_in[8];
    const float* cg_w2    = (const float*)d_in[9];
    const float* cg_b2    = (const float*)d_in[10];
    const float* lf_w1    = (const float*)d_in[11];
    const float* lf_b1    = (const float*)d_in[12];
    const float* lf_w2    = (const float*)d_in[13];
    const float* lf_b2    = (const float*)d_in[14];

    float* out = (float*)d_out;
    const size_t N_GF = (size_t)B_ * C_ * HW;   // 33554432
    float* out_gf    = out;
    float* out_gl    = out_gf + N_GF;           // 8192
    float* out_boxes = out_gl + (size_t)B_ * C_; // 128
    float* out_rm    = out_boxes + B_ * 4;      // 131072
    float* out_pf    = out_rm + (size_t)B_ * HW; // 8192

    float* wsf     = (float*)d_ws;
    float* ws_area = wsf;                 // 32
    float* ws_hcg  = wsf + 32;            // 8192
    float* ws_hlf  = ws_hcg + B_ * C_;    // 8192
    float* ws_cg   = ws_hlf + B_ * C_;    // 8192

    kern_mask<<<B_, 256, 0, stream>>>(xywh, conv1_w, conv1_b, conv2_w, conv2_b,
                                      out_boxes, out_rm, ws_area);
    kern_pf<<<B_ * C_, 256, 0, stream>>>(feat, out_rm, ws_area, out_pf);
    kern_mlp1<<<B_, 256, 0, stream>>>(out_pf, lang, cg_w1, cg_b1, lf_w1, lf_b1,
                                      ws_hcg, ws_hlf);
    kern_mlp2<<<B_, 256, 0, stream>>>(ws_hcg, ws_hlf, cg_w2, cg_b2, lf_w2, lf_b2,
                                      lang, ws_cg, out_gl);
    kern_guided<<<B_ * C_, 256, 0, stream>>>(feat, out_rm, ws_cg, out_gf);
}

// Round 2
// 95.136 us; speedup vs baseline: 1.3054x; 1.3054x over previous
//
#include <hip/hip_runtime.h>
#include <math.h>

#define B_  32
#define C_  256
#define H_  64
#define W_  64
#define HW  (H_*W_)          // 4096
#define HW4 (HW/4)           // 1024

typedef float f32x4 __attribute__((ext_vector_type(4)));

__device__ __forceinline__ float clamp01(float v) {
    return fminf(fmaxf(v, 0.0f), 1.0f);
}

__device__ __forceinline__ float block_reduce_sum_256(float v, float* sm) {
    #pragma unroll
    for (int off = 32; off > 0; off >>= 1) v += __shfl_down(v, off, 64);
    int lane = threadIdx.x & 63, wid = threadIdx.x >> 6;
    if (lane == 0) sm[wid] = v;
    __syncthreads();
    float total = 0.0f;
    if (threadIdx.x == 0) total = sm[0] + sm[1] + sm[2] + sm[3];
    return total;
}

// Kernel A: 4 blocks per batch. boxes -> analytic mask -> conv1(3x3,16)+relu
// -> conv2(1x1)+sigmoid -> refined_mask out + partial area to ws.
__global__ __launch_bounds__(256) void kern_mask(
    const float* __restrict__ xywh,
    const float* __restrict__ conv1_w, const float* __restrict__ conv1_b,
    const float* __restrict__ conv2_w, const float* __restrict__ conv2_b,
    float* __restrict__ out_boxes, float* __restrict__ out_rm,
    float* __restrict__ ws_part)
{
    const int b = blockIdx.x >> 2;
    const int q = blockIdx.x & 3;        // quarter of the image
    const int t = threadIdx.x;

    __shared__ float sw1[16 * 9];
    __shared__ float sb1[16];
    __shared__ float sw2[16];
    __shared__ float sred[4];

    if (t < 144)                 sw1[t]       = conv1_w[t];
    else if (t < 160)            sb1[t - 144] = conv1_b[t - 144];
    else if (t < 176)            sw2[t - 160] = conv2_w[t - 160];
    const float b2v = conv2_b[0];

    const float xc = xywh[b * 4 + 0];
    const float yc = xywh[b * 4 + 1];
    const float bw = xywh[b * 4 + 2];
    const float bh = xywh[b * 4 + 3];

    float x1 = clamp01(xc - bw * 0.5f);
    float y1 = clamp01(yc - bh * 0.5f);
    float x2 = clamp01(xc + bw * 0.5f);
    float y2 = clamp01(yc + bh * 0.5f);
    float xl = fminf(x1, x2), xh = fmaxf(x1, x2);
    float yl = fminf(y1, y2), yh = fmaxf(y1, y2);
    float w_ = fmaxf(xh - xl, 1e-6f);
    float h_ = fmaxf(yh - yl, 1e-6f);
    float cx = (xh + xl) * 0.5f, cy = (yh + yl) * 0.5f;
    float bx1 = clamp01(cx - w_ * 0.5f);
    float by1 = clamp01(cy - h_ * 0.5f);
    float bx2 = clamp01(cx + w_ * 0.5f);
    float by2 = clamp01(cy + h_ * 0.5f);

    if (t == 0 && q == 0) {
        out_boxes[b * 4 + 0] = bx1;
        out_boxes[b * 4 + 1] = by1;
        out_boxes[b * 4 + 2] = bx2;
        out_boxes[b * 4 + 3] = by2;
    }

    float ww = fmaxf(bx2 - bx1, 1e-4f);
    float hh = fmaxf(by2 - by1, 1e-4f);
    float diag = sqrtf(ww * ww + hh * hh);
    float margin = fminf(fmaxf(diag * 0.2f, 0.02f), 0.2f);
    float mx1 = clamp01(bx1 - margin);
    float my1 = clamp01(by1 - margin);
    float mx2 = clamp01(bx2 + margin);
    float my2 = clamp01(by2 + margin);

    __syncthreads();

    float asum = 0.0f;
    const int p0 = q * 1024;
    for (int pi = t; pi < 1024; pi += 256) {
        const int p = p0 + pi;
        const int y = p >> 6;
        const int x = p & 63;
        float mv[9];
        #pragma unroll
        for (int ky = 0; ky < 3; ++ky) {
            const int yy = y + ky - 1;
            float gy = (float)((double)yy / 63.0);
            bool yin = (yy >= 0) && (yy < H_) && (gy >= my1) && (gy <= my2);
            #pragma unroll
            for (int kx = 0; kx < 3; ++kx) {
                const int xx = x + kx - 1;
                float gx = (float)((double)xx / 63.0);
                bool xin = (xx >= 0) && (xx < W_) && (gx >= mx1) && (gx <= mx2);
                mv[ky * 3 + kx] = (yin && xin) ? 1.0f : 0.0f;
            }
        }
        float z = b2v;
        #pragma unroll
        for (int oc = 0; oc < 16; ++oc) {
            float hsum = sb1[oc];
            #pragma unroll
            for (int k = 0; k < 9; ++k) hsum = fmaf(mv[k], sw1[oc * 9 + k], hsum);
            z = fmaf(fmaxf(hsum, 0.0f), sw2[oc], z);
        }
        float rm = 1.0f / (1.0f + expf(-z));
        out_rm[b * HW + p] = rm;
        asum += rm;
    }

    float total = block_reduce_sum_256(asum, sred);
    if (t == 0) ws_part[b * 4 + q] = total;
}

// Kernel B: pointer_feat[b,c] = sum(feat[b,c,:,:] * rm[b,:,:]) / area[b]
// 2 channels per block -> rm row read once per pair.
__global__ __launch_bounds__(256) void kern_pf(
    const float* __restrict__ feat, const float* __restrict__ rm,
    const float* __restrict__ ws_part, float* __restrict__ out_pf)
{
    const int blk = blockIdx.x;          // b*128 + cp
    const int b = blk >> 7;
    const int c0 = (blk & 127) * 2;
    __shared__ float2 sred[4];

    const size_t row0 = ((size_t)b * C_ + c0) * HW;
    const f32x4* f0 = (const f32x4*)(feat + row0);
    const f32x4* f1 = f0 + HW4;
    const f32x4* r4 = (const f32x4*)(rm + (size_t)b * HW);

    float s0 = 0.0f, s1 = 0.0f;
    for (int i = threadIdx.x; i < HW4; i += 256) {
        f32x4 r = r4[i];
        f32x4 a = f0[i];
        f32x4 c = f1[i];
        s0 = fmaf(a.x, r.x, fmaf(a.y, r.y, fmaf(a.z, r.z, fmaf(a.w, r.w, s0))));
        s1 = fmaf(c.x, r.x, fmaf(c.y, r.y, fmaf(c.z, r.z, fmaf(c.w, r.w, s1))));
    }
    // two-value block reduce
    #pragma unroll
    for (int off = 32; off > 0; off >>= 1) {
        s0 += __shfl_down(s0, off, 64);
        s1 += __shfl_down(s1, off, 64);
    }
    int lane = threadIdx.x & 63, wid = threadIdx.x >> 6;
    if (lane == 0) sred[wid] = make_float2(s0, s1);
    __syncthreads();
    if (threadIdx.x == 0) {
        float t0 = sred[0].x + sred[1].x + sred[2].x + sred[3].x;
        float t1 = sred[0].y + sred[1].y + sred[2].y + sred[3].y;
        float area = fmaxf(ws_part[b * 4 + 0] + ws_part[b * 4 + 1] +
                           ws_part[b * 4 + 2] + ws_part[b * 4 + 3], 1.0f);
        out_pf[b * C_ + c0]     = t0 / area;
        out_pf[b * C_ + c0 + 1] = t1 / area;
    }
}

// Kernel C: fused 2-layer MLP. 2 blocks per batch: which=0 -> ch_gate,
// which=1 -> guided_lang. Hidden layer lives in LDS.
__global__ __launch_bounds__(256) void kern_mlp(
    const float* __restrict__ pf, const float* __restrict__ lang,
    const float* __restrict__ cg_w1, const float* __restrict__ cg_b1,
    const float* __restrict__ cg_w2, const float* __restrict__ cg_b2,
    const float* __restrict__ lf_w1, const float* __restrict__ lf_b1,
    const float* __restrict__ lf_w2, const float* __restrict__ lf_b2,
    float* __restrict__ ws_cg, float* __restrict__ out_gl)
{
    const int b = blockIdx.x >> 1;
    const int which = blockIdx.x & 1;
    const int t = threadIdx.x;
    __shared__ float fus[512];
    __shared__ float hid[256];

    fus[t]       = pf[b * 256 + t];
    fus[256 + t] = lang[b * 256 + t];

    const float* w1 = which ? lf_w1 : cg_w1;
    const float* b1 = which ? lf_b1 : cg_b1;
    const float* w2 = which ? lf_w2 : cg_w2;
    const float* b2 = which ? lf_b2 : cg_b2;
    __syncthreads();

    const f32x4* wv = (const f32x4*)(w1 + (size_t)t * 512);
    const f32x4* fv = (const f32x4*)fus;
    float s = 0.0f;
    #pragma unroll 4
    for (int k = 0; k < 128; ++k) {
        f32x4 f = fv[k], w = wv[k];
        s = fmaf(f.x, w.x, fmaf(f.y, w.y, fmaf(f.z, w.z, fmaf(f.w, w.w, s))));
    }
    hid[t] = fmaxf(s + b1[t], 0.0f);
    __syncthreads();

    const f32x4* w2v = (const f32x4*)(w2 + (size_t)t * 256);
    const f32x4* hv = (const f32x4*)hid;
    float s2 = 0.0f;
    #pragma unroll 4
    for (int k = 0; k < 64; ++k) {
        f32x4 h = hv[k], w = w2v[k];
        s2 = fmaf(h.x, w.x, fmaf(h.y, w.y, fmaf(h.z, w.z, fmaf(h.w, w.w, s2))));
    }
    s2 += b2[t];
    if (which == 0) {
        ws_cg[b * 256 + t] = 1.0f / (1.0f + expf(-s2));
    } else {
        out_gl[b * 256 + t] = fus[256 + t] + 0.4f * tanhf(s2);
    }
}

// Kernel E: guided_feat = feat * (1 + 0.6*rm) * (1 + 0.5*cg).
// 2 channel rows per block; non-temporal stores (out never re-read; keep
// feat resident in L2/L3 for its second pass).
__global__ __launch_bounds__(256) void kern_guided(
    const float* __restrict__ feat, const float* __restrict__ rm,
    const float* __restrict__ ws_cg, float* __restrict__ out_gf)
{
    const int blk = blockIdx.x;          // b*128 + cp
    const int b = blk >> 7;
    const int c0 = (blk & 127) * 2;
    const float g0 = 1.0f + 0.5f * ws_cg[b * C_ + c0];
    const float g1 = 1.0f + 0.5f * ws_cg[b * C_ + c0 + 1];

    const size_t row0 = ((size_t)b * C_ + c0) * HW;
    const f32x4* f0 = (const f32x4*)(feat + row0);
    const f32x4* f1 = f0 + HW4;
    const f32x4* r4 = (const f32x4*)(rm + (size_t)b * HW);
    f32x4* o0 = (f32x4*)(out_gf + row0);
    f32x4* o1 = o0 + HW4;

    for (int i = threadIdx.x; i < HW4; i += 256) {
        f32x4 r = r4[i];
        f32x4 m;
        m.x = 1.0f + 0.6f * r.x;
        m.y = 1.0f + 0.6f * r.y;
        m.z = 1.0f + 0.6f * r.z;
        m.w = 1.0f + 0.6f * r.w;
        f32x4 a = f0[i];
        f32x4 c = f1[i];
        f32x4 oa, ob;
        oa.x = a.x * m.x * g0;  oa.y = a.y * m.y * g0;
        oa.z = a.z * m.z * g0;  oa.w = a.w * m.w * g0;
        ob.x = c.x * m.x * g1;  ob.y = c.y * m.y * g1;
        ob.z = c.z * m.z * g1;  ob.w = c.w * m.w * g1;
        __builtin_nontemporal_store(oa, &o0[i]);
        __builtin_nontemporal_store(ob, &o1[i]);
    }
}

extern "C" void kernel_launch(void* const* d_in, const int* in_sizes, int n_in,
                              void* d_out, int out_size, void* d_ws, size_t ws_size,
                              hipStream_t stream) {
    const float* feat     = (const float*)d_in[0];
    const float* lang     = (const float*)d_in[1];
    const float* xywh     = (const float*)d_in[2];
    const float* conv1_w  = (const float*)d_in[3];
    const float* conv1_b  = (const float*)d_in[4];
    const float* conv2_w  = (const float*)d_in[5];
    const float* conv2_b  = (const float*)d_in[6];
    const float* cg_w1    = (const float*)d_in[7];
    const float* cg_b1    = (const float*)d_in[8];
    const float* cg_w2    = (const float*)d_in[9];
    const float* cg_b2    = (const float*)d_in[10];
    const float* lf_w1    = (const float*)d_in[11];
    const float* lf_b1    = (const float*)d_in[12];
    const float* lf_w2    = (const float*)d_in[13];
    const float* lf_b2    = (const float*)d_in[14];

    float* out = (float*)d_out;
    const size_t N_GF = (size_t)B_ * C_ * HW;   // 33554432
    float* out_gf    = out;
    float* out_gl    = out_gf + N_GF;            // 8192
    float* out_boxes = out_gl + (size_t)B_ * C_; // 128
    float* out_rm    = out_boxes + B_ * 4;       // 131072
    float* out_pf    = out_rm + (size_t)B_ * HW; // 8192

    float* wsf     = (float*)d_ws;
    float* ws_part = wsf;                  // 128 partial area sums
    float* ws_cg   = wsf + 128;            // 8192
    float* ws_pf   = ws_cg + B_ * C_;      // (unused spare)

    (void)ws_pf; (void)ws_size; (void)in_sizes; (void)n_in; (void)out_size;

    kern_mask<<<B_ * 4, 256, 0, stream>>>(xywh, conv1_w, conv1_b, conv2_w, conv2_b,
                                          out_boxes, out_rm, ws_part);
    kern_pf<<<B_ * C_ / 2, 256, 0, stream>>>(feat, out_rm, ws_part, out_pf);
    kern_mlp<<<B_ * 2, 256, 0, stream>>>(out_pf, lang,
                                         cg_w1, cg_b1, cg_w2, cg_b2,
                                         lf_w1, lf_b1, lf_w2, lf_b2,
                                         ws_cg, out_gl);
    kern_guided<<<B_ * C_ / 2, 256, 0, stream>>>(feat, out_rm, ws_cg, out_gf);
}